// Round 12
// baseline (63.482 us; speedup 1.0000x reference)
//
#include <hip/hip_runtime.h>
#include <math.h>

#define NN 256
#define XX 256
#define TT 3
#define KK 64
#define AA 193          // 3*K+1
#define EPSF 1e-9f
#define NPART 256
#define NBLK 4096       // 3072 stream + 1024 pairs, interleaved 3:1

// ws layout (bytes):
// [0, 2048)            double part[256]
// [2048, 3072)         int nsel[256]
// [3072, 4096)         int ncols[256]
// [4096, 266240)       int S[256][256]      (full `order` per n)
// [266240, 331776)     int Ck[256][64]      (full `corder` per n)
// [331776, 1118208)    float mask[196608]   (gt_class value per row, 0.0/1.0)

typedef float float4a __attribute__((ext_vector_type(4)));

__device__ __forceinline__ float4a ld4(const float* p) {
    float4a v;
    __builtin_memcpy(&v, p, 16);   // align-4 safe
    return v;
}

// 1024 threads: phase 1 on waves 0-3 (one x per thread), phase 2 on all 16 waves.
__global__ __launch_bounds__(1024) void k_meta(const float* __restrict__ gt,
                                               int* __restrict__ nselArr,
                                               int* __restrict__ ncolsArr,
                                               int* __restrict__ S,
                                               int* __restrict__ Ck,
                                               double* __restrict__ part,
                                               float* __restrict__ mask) {
    int n = blockIdx.x;
    int tid = threadIdx.x;
    int lane = tid & 63;
    int wave = tid >> 6;
    bool isP1 = wave < 4;          // tid < 256, wave-uniform

    // zero the partial-sum buffer (consumers launch after us on the stream)
    if (n == 0 && tid < NPART) part[tid] = 0.0;

    __shared__ int s_S[XX];
    __shared__ int s_cnt[4];
    __shared__ float s_red[16 * 64];
    __shared__ int s_nsel;

    // ---- phase 1a: load gc, write mask, ballot ----
    bool selx = false;
    unsigned long long bal = 0;
    if (isP1) {
        int x = tid;
        size_t rb = ((size_t)(n * XX + x) * TT) * AA;
        float gc0 = gt[rb + 3 * KK];
        float gc1 = gt[rb + AA + 3 * KK];
        float gc2 = gt[rb + 2 * AA + 3 * KK];
        int rowid = (n * XX + x) * TT;
        mask[rowid + 0] = gc0;
        mask[rowid + 1] = gc1;
        mask[rowid + 2] = gc2;
        selx = gc0 > 0.0f;
        bal = __ballot(selx);
        if (lane == 0) s_cnt[wave] = __popcll(bal);
    }
    __syncthreads();

    // ---- phase 1b: stable partition (the `order` array) ----
    if (isP1) {
        int c0 = s_cnt[0], c1 = s_cnt[1], c2 = s_cnt[2], c3 = s_cnt[3];
        int nsel_n = c0 + c1 + c2 + c3;
        int selbase = (wave > 0 ? c0 : 0) + (wave > 1 ? c1 : 0) + (wave > 2 ? c2 : 0);
        unsigned long long ltmask = (1ull << lane) - 1ull;
        int pos;
        if (selx) pos = selbase + __popcll(bal & ltmask);
        else      pos = nsel_n + (64 * wave - selbase) + __popcll((~bal) & ltmask);
        s_S[pos] = tid;
        if (tid == 0) { s_nsel = nsel_n; nselArr[n] = nsel_n; }
    }
    __syncthreads();
    if (tid < XX) S[n * XX + tid] = s_S[tid];

    // ---- phase 2: column sums over selected rows (16 waves) ----
    int nsl = s_nsel;
    float partial = 0.0f;
    for (int i = wave; i < nsl; i += 16) {
        int xs = s_S[i];
        size_t base = ((size_t)(n * XX + xs) * TT) * AA + 2 * KK + lane;
        partial += gt[base] + gt[base + AA] + gt[base + 2 * AA];
    }
    s_red[tid] = partial;
    __syncthreads();

    // ---- phase 3: keep + stable column partition (the `corder` array) ----
    if (tid < KK) {
        float tot = 0.0f;
        #pragma unroll
        for (int w = 0; w < 16; ++w) tot += s_red[tid + 64 * w];
        int nrows = nsl * TT;
        bool keep = (tot >= (float)nrows) || (tid < 5);
        unsigned long long kb = __ballot(keep);
        int nc = __popcll(kb);
        unsigned long long lt = (1ull << tid) - 1ull;
        int cpos = keep ? __popcll(kb & lt) : nc + __popcll((~kb) & lt);
        Ck[n * KK + cpos] = tid;
        if (tid == 0) ncolsArr[n] = nc;
    }
}

// Role-split fused kernel, 3:1 stream:pairs interleave, XCD-chunk swizzled so
// batch n's stream blocks AND its 4 pairs blocks land on ONE XCD's L2
// (works [512x, 512x+512) = batches [32x, 32x+32) on XCD x). Stream waves
// walk 4 CONSECUTIVE groups (16 consecutive rows) for linear DRAM locality.
__global__ __launch_bounds__(256) void k_fused(const float* __restrict__ pred,
                                               const float* __restrict__ gt,
                                               const float* __restrict__ mask,
                                               const float* __restrict__ hcam_arr,
                                               const float* __restrict__ ax,
                                               const float* __restrict__ ay,
                                               const float* __restrict__ xstd,
                                               const float* __restrict__ zstd,
                                               const int* __restrict__ nselArr,
                                               const int* __restrict__ ncolsArr,
                                               const int* __restrict__ S,
                                               const int* __restrict__ Ck,
                                               double* __restrict__ part) {
    int tid = threadIdx.x;
    int lane = tid & 63;
    int wid = tid >> 6;
    // XCD chunk swizzle: dispatch d -> XCD d%8 (round-robin); give XCD x the
    // contiguous work range [512x, 512x+512).
    int w = ((blockIdx.x & 7) << 9) | (blockIdx.x >> 3);

    float local = 0.0f;

    if ((w & 3) == 3) {
        // ---- pairs role: idx 0..1023, 4 blocks per n, 16 waves per n ----
        float accp = 0.0f;
        int idx = w >> 2;
        int n = idx >> 2;
        int waveIdx = ((idx & 3) << 2) | wid;          // 0..15
        int nrows = nselArr[n] * TT;
        int ncols = ncolsArr[n];
        int k = Ck[n * KK + lane];
        float inv_h = 1.0f / hcam_arr[n];
        float zs = zstd[k], xs = xstd[k], ayk = ay[k];
        float xstd0 = xstd[0];

        for (int i = 0; i < 48; ++i) {
            int p = i * 16 + waveIdx;                  // covers 0..767
            if (p + 1 >= nrows) break;                 // wave-uniform, monotone
            int r1 = p + 1;
            int x0 = S[n * XX + p / 3];  int t0 = p % 3;
            int x1 = S[n * XX + r1 / 3]; int t1 = r1 % 3;
            size_t b0 = ((size_t)(n * XX + x0) * TT + t0) * AA;
            size_t b1 = ((size_t)(n * XX + x1) * TT + t1) * AA;
            float pz0 = pred[b0 + KK + k], gx0 = gt[b0 + k];
            float pz1 = pred[b1 + KK + k], gx1 = gt[b1 + k];
            float ax0 = ax[x0], ax1 = ax[x1];
            float Z0 = pz0 * zs, Z1 = pz1 * zs;
            float sc0 = 1.0f - Z0 * inv_h, sc1 = 1.0f - Z1 * inv_h;
            float L0 = sc0 * (gx0 * xs + ax0);
            float L1 = sc1 * (gx1 * xs + ax1);
            float Y0 = sc0 * ayk;
            float l00 = gt[b0] * xstd0 + ax0;
            float l01 = gt[b1] * xstd0 + ax1;
            float width0 = fabsf(l01 - l00);

            float lm1 = __shfl_up(L0, 1);
            float ym1 = __shfl_up(Y0, 1);
            float y1v = __shfl(Y0, 1);
            float dYc, lc;
            if (lane == 0) {
                dYc = fabsf(y1v - Y0);
                lc = dYc;
            } else {
                dYc = fabsf(Y0 - ym1);
                float dx = L0 - lm1;
                lc = sqrtf(dx * dx + dYc * dYc);
            }
            float wv = fabsf(L1 - L0) * dYc / (lc + EPSF);
            float wm1 = __shfl_up(wv, 1);
            float werr = fabsf(wv - (lane == 0 ? width0 : wm1));
            float dZ = fabsf(Z1 - Z0);
            if (lane < ncols) accp += werr + dZ;
        }
        local = 5.0f * accp;
    } else {
        // ---- stream role: s 0..3071, wave owns 4 CONSECUTIVE groups ----
        int s = (w >> 2) * 3 + (w & 3);
        int sub = lane & 15;        // 16-B chunk within the 256-B field
        int rr = lane >> 4;         // row within group of 4
        int gbase = s * 16 + wid * 4;

        // prefetch the 4 row-mask predicates (mask is 786 KB, L2-resident)
        float mk[4];
        #pragma unroll
        for (int j = 0; j < 4; ++j) mk[j] = mask[4 * (gbase + j) + rr];

        float a0 = 0.0f, a12 = 0.0f;
        #pragma unroll
        for (int h = 0; h < 2; ++h) {
            size_t b0 = (size_t)(4 * (gbase + 2 * h) + rr) * AA;
            size_t b1 = (size_t)(4 * (gbase + 2 * h + 1) + rr) * AA;
            bool m0 = mk[2 * h] > 0.0f, m1 = mk[2 * h + 1] > 0.0f;

            float4a pv0 = ld4(pred + b0 + 2 * KK + sub * 4);
            float4a gv0 = ld4(gt   + b0 + 2 * KK + sub * 4);
            float4a pv1 = ld4(pred + b1 + 2 * KK + sub * 4);
            float4a gv1 = ld4(gt   + b1 + 2 * KK + sub * 4);
            float pc0 = pred[b0 + 3 * KK];
            float pc1 = pred[b1 + 3 * KK];
            float4a pX0 = {0,0,0,0}, gX0 = {0,0,0,0}, pX1 = {0,0,0,0}, gX1 = {0,0,0,0};
            if (m0) { pX0 = ld4(pred + b0 + sub * 4); gX0 = ld4(gt + b0 + sub * 4); }
            if (m1) { pX1 = ld4(pred + b1 + sub * 4); gX1 = ld4(gt + b1 + sub * 4); }

            // BCE select values; all in (0.01, 1.0) -> product of 8 safe
            float s0 = gv0.x > 0.0f ? pv0.x + EPSF : 1.0f - pv0.x + EPSF;
            float s1 = gv0.y > 0.0f ? pv0.y + EPSF : 1.0f - pv0.y + EPSF;
            float s2 = gv0.z > 0.0f ? pv0.z + EPSF : 1.0f - pv0.z + EPSF;
            float s3 = gv0.w > 0.0f ? pv0.w + EPSF : 1.0f - pv0.w + EPSF;
            float s4 = gv1.x > 0.0f ? pv1.x + EPSF : 1.0f - pv1.x + EPSF;
            float s5 = gv1.y > 0.0f ? pv1.y + EPSF : 1.0f - pv1.y + EPSF;
            float s6 = gv1.z > 0.0f ? pv1.z + EPSF : 1.0f - pv1.z + EPSF;
            float s7 = gv1.w > 0.0f ? pv1.w + EPSF : 1.0f - pv1.w + EPSF;
            a0 += __logf(((s0 * s1) * (s2 * s3)) * ((s4 * s5) * (s6 * s7)));

            if (sub == 0) {
                float c0 = m0 ? pc0 + EPSF : 1.0f - pc0 + EPSF;
                float c1 = m1 ? pc1 + EPSF : 1.0f - pc1 + EPSF;
                a12 -= __logf(c0 * c1);
            }

            if (m0)
                a12 += gv0.x * fabsf(pX0.x - gX0.x) + gv0.y * fabsf(pX0.y - gX0.y)
                     + gv0.z * fabsf(pX0.z - gX0.z) + gv0.w * fabsf(pX0.w - gX0.w);
            if (m1)
                a12 += gv1.x * fabsf(pX1.x - gX1.x) + gv1.y * fabsf(pX1.y - gX1.y)
                     + gv1.z * fabsf(pX1.z - gX1.z) + gv1.w * fabsf(pX1.w - gX1.w);
        }
        local = a12 - a0 * (1.0f / KK);
    }

    // ---- wave reduce (no barriers) + cross-wave + one atomic per block ----
    #pragma unroll
    for (int d = 32; d > 0; d >>= 1) local += __shfl_xor(local, d);

    __shared__ float s_w[4];
    if (lane == 0) s_w[wid] = local;
    __syncthreads();
    if (tid == 0) {
        float tot = s_w[0] + s_w[1] + s_w[2] + s_w[3];
        atomicAdd(&part[blockIdx.x & (NPART - 1)], (double)tot);
    }
}

__global__ __launch_bounds__(256) void k_final(const double* __restrict__ part,
                                               float* __restrict__ out) {
    int tid = threadIdx.x;
    __shared__ double red[256];
    red[tid] = part[tid];
    __syncthreads();
    for (int s = 128; s > 0; s >>= 1) {
        if (tid < s) red[tid] += red[tid + s];
        __syncthreads();
    }
    if (tid == 0) out[0] = (float)red[0];
}

extern "C" void kernel_launch(void* const* d_in, const int* in_sizes, int n_in,
                              void* d_out, int out_size, void* d_ws, size_t ws_size,
                              hipStream_t stream) {
    const float* pred = (const float*)d_in[0];
    const float* gt   = (const float*)d_in[1];
    const float* hcam = (const float*)d_in[2];
    const float* ax   = (const float*)d_in[3];
    const float* ay   = (const float*)d_in[4];
    const float* xstd = (const float*)d_in[5];
    const float* zstd = (const float*)d_in[6];
    float* out = (float*)d_out;

    char* ws = (char*)d_ws;
    double* part = (double*)ws;
    int* nsel   = (int*)(ws + 2048);
    int* ncols  = (int*)(ws + 3072);
    int* S      = (int*)(ws + 4096);
    int* Ck     = (int*)(ws + 266240);
    float* mask = (float*)(ws + 331776);

    hipLaunchKernelGGL(k_meta, dim3(NN), dim3(1024), 0, stream,
                       gt, nsel, ncols, S, Ck, part, mask);
    hipLaunchKernelGGL(k_fused, dim3(NBLK), dim3(256), 0, stream,
                       pred, gt, mask, hcam, ax, ay, xstd, zstd,
                       nsel, ncols, S, Ck, part);
    hipLaunchKernelGGL(k_final, dim3(1), dim3(256), 0, stream, part, out);
}

// Round 13
// 49.366 us; speedup vs baseline: 1.2860x; 1.2860x over previous
//
#include <hip/hip_runtime.h>
#include <math.h>

#define NN 256
#define XX 256
#define TT 3
#define KK 64
#define AA 193          // 3*K+1
#define EPSF 1e-9f
#define NPART 256
#define SBLK 2048       // stream-role blocks
#define PBLK 2048       // pairs-role blocks (8 per n)
#define NBLK (SBLK + PBLK)   // 4096 = 8 * 512 (bijective XCD swizzle)

// ws layout (bytes):
// [0, 2048)            double part[256]
// [2048, 3072)         int nsel[256]
// [3072, 4096)         int ncols[256]
// [4096, 266240)       int S[256][256]      (full `order` per n)
// [266240, 331776)     int Ck[256][64]      (full `corder` per n)
// [331776, 1118208)    float mask[196608]   (gt_class value per row, 0.0/1.0)

typedef float float4a __attribute__((ext_vector_type(4)));

__device__ __forceinline__ float4a ld4(const float* p) {
    float4a v;
    __builtin_memcpy(&v, p, 16);   // align-4 safe
    return v;
}

// 1024 threads: phase 1 on waves 0-3 (one x per thread), phase 2 on all 16 waves.
__global__ __launch_bounds__(1024) void k_meta(const float* __restrict__ gt,
                                               int* __restrict__ nselArr,
                                               int* __restrict__ ncolsArr,
                                               int* __restrict__ S,
                                               int* __restrict__ Ck,
                                               double* __restrict__ part,
                                               float* __restrict__ mask) {
    int n = blockIdx.x;
    int tid = threadIdx.x;
    int lane = tid & 63;
    int wave = tid >> 6;
    bool isP1 = wave < 4;          // tid < 256, wave-uniform

    // zero the partial-sum buffer (consumers launch after us on the stream)
    if (n == 0 && tid < NPART) part[tid] = 0.0;

    __shared__ int s_S[XX];
    __shared__ int s_cnt[4];
    __shared__ float s_red[16 * 64];
    __shared__ int s_nsel;

    // ---- phase 1a: load gc, write mask, ballot ----
    bool selx = false;
    unsigned long long bal = 0;
    if (isP1) {
        int x = tid;
        size_t rb = ((size_t)(n * XX + x) * TT) * AA;
        float gc0 = gt[rb + 3 * KK];
        float gc1 = gt[rb + AA + 3 * KK];
        float gc2 = gt[rb + 2 * AA + 3 * KK];
        int rowid = (n * XX + x) * TT;
        mask[rowid + 0] = gc0;
        mask[rowid + 1] = gc1;
        mask[rowid + 2] = gc2;
        selx = gc0 > 0.0f;
        bal = __ballot(selx);
        if (lane == 0) s_cnt[wave] = __popcll(bal);
    }
    __syncthreads();

    // ---- phase 1b: stable partition (the `order` array) ----
    if (isP1) {
        int c0 = s_cnt[0], c1 = s_cnt[1], c2 = s_cnt[2], c3 = s_cnt[3];
        int nsel_n = c0 + c1 + c2 + c3;
        int selbase = (wave > 0 ? c0 : 0) + (wave > 1 ? c1 : 0) + (wave > 2 ? c2 : 0);
        unsigned long long ltmask = (1ull << lane) - 1ull;
        int pos;
        if (selx) pos = selbase + __popcll(bal & ltmask);
        else      pos = nsel_n + (64 * wave - selbase) + __popcll((~bal) & ltmask);
        s_S[pos] = tid;
        if (tid == 0) { s_nsel = nsel_n; nselArr[n] = nsel_n; }
    }
    __syncthreads();
    if (tid < XX) S[n * XX + tid] = s_S[tid];

    // ---- phase 2: column sums over selected rows (16 waves) ----
    int nsl = s_nsel;
    float partial = 0.0f;
    for (int i = wave; i < nsl; i += 16) {
        int xs = s_S[i];
        size_t base = ((size_t)(n * XX + xs) * TT) * AA + 2 * KK + lane;
        partial += gt[base] + gt[base + AA] + gt[base + 2 * AA];
    }
    s_red[tid] = partial;
    __syncthreads();

    // ---- phase 3: keep + stable column partition (the `corder` array) ----
    if (tid < KK) {
        float tot = 0.0f;
        #pragma unroll
        for (int w = 0; w < 16; ++w) tot += s_red[tid + 64 * w];
        int nrows = nsl * TT;
        bool keep = (tot >= (float)nrows) || (tid < 5);
        unsigned long long kb = __ballot(keep);
        int nc = __popcll(kb);
        unsigned long long lt = (1ull << tid) - 1ull;
        int cpos = keep ? __popcll(kb & lt) : nc + __popcll((~kb) & lt);
        Ck[n * KK + cpos] = tid;
        if (tid == 0) ncolsArr[n] = nc;
    }
}

// R11 structure (1:1 role interleave, strided stream groups, 32 pairs-waves/n)
// + bijective XCD chunk swizzle ONLY: dispatch d -> XCD d%8; XCD x owns works
// [512x, 512x+512), so batch n's 8 pairs blocks share ONE L2 (pairs working
// set ~800KB/n fits in 4MB). Stream role unchanged (bijection = same coverage).
__global__ __launch_bounds__(256) void k_fused(const float* __restrict__ pred,
                                               const float* __restrict__ gt,
                                               const float* __restrict__ mask,
                                               const float* __restrict__ hcam_arr,
                                               const float* __restrict__ ax,
                                               const float* __restrict__ ay,
                                               const float* __restrict__ xstd,
                                               const float* __restrict__ zstd,
                                               const int* __restrict__ nselArr,
                                               const int* __restrict__ ncolsArr,
                                               const int* __restrict__ S,
                                               const int* __restrict__ Ck,
                                               double* __restrict__ part) {
    int tid = threadIdx.x;
    int lane = tid & 63;
    int wid = tid >> 6;
    // bijective XCD chunk swizzle (NBLK = 4096 = 8 * 512)
    int w = ((blockIdx.x & 7) << 9) | (blockIdx.x >> 3);
    int role_pairs = w & 1;
    int idx = w >> 1;                   // 0..2047 within each role

    float local = 0.0f;

    if (role_pairs) {
        // ---- pairs role: 8 blocks per n, 32 waves per n ----
        float accp = 0.0f;
        int n = idx >> 3;
        int waveIdx = ((idx & 7) << 2) | wid;          // 0..31
        int nrows = nselArr[n] * TT;
        int ncols = ncolsArr[n];
        int k = Ck[n * KK + lane];
        float inv_h = 1.0f / hcam_arr[n];
        float zs = zstd[k], xs = xstd[k], ayk = ay[k];
        float xstd0 = xstd[0];

        for (int i = 0; i < 24; ++i) {
            int p = i * 32 + waveIdx;                  // covers 0..767
            if (p + 1 >= nrows) break;                 // wave-uniform, monotone
            int r1 = p + 1;
            int x0 = S[n * XX + p / 3];  int t0 = p % 3;
            int x1 = S[n * XX + r1 / 3]; int t1 = r1 % 3;
            size_t b0 = ((size_t)(n * XX + x0) * TT + t0) * AA;
            size_t b1 = ((size_t)(n * XX + x1) * TT + t1) * AA;
            float pz0 = pred[b0 + KK + k], gx0 = gt[b0 + k];
            float pz1 = pred[b1 + KK + k], gx1 = gt[b1 + k];
            float ax0 = ax[x0], ax1 = ax[x1];
            float Z0 = pz0 * zs, Z1 = pz1 * zs;
            float sc0 = 1.0f - Z0 * inv_h, sc1 = 1.0f - Z1 * inv_h;
            float L0 = sc0 * (gx0 * xs + ax0);
            float L1 = sc1 * (gx1 * xs + ax1);
            float Y0 = sc0 * ayk;
            float l00 = gt[b0] * xstd0 + ax0;
            float l01 = gt[b1] * xstd0 + ax1;
            float width0 = fabsf(l01 - l00);

            float lm1 = __shfl_up(L0, 1);
            float ym1 = __shfl_up(Y0, 1);
            float y1v = __shfl(Y0, 1);
            float dYc, lc;
            if (lane == 0) {
                dYc = fabsf(y1v - Y0);
                lc = dYc;
            } else {
                dYc = fabsf(Y0 - ym1);
                float dx = L0 - lm1;
                lc = sqrtf(dx * dx + dYc * dYc);
            }
            float wv = fabsf(L1 - L0) * dYc / (lc + EPSF);
            float wm1 = __shfl_up(wv, 1);
            float werr = fabsf(wv - (lane == 0 ? width0 : wm1));
            float dZ = fabsf(Z1 - Z0);
            if (lane < ncols) accp += werr + dZ;
        }
        local = 5.0f * accp;
    } else {
        // ---- stream role: loss0 + loss1 + loss2 (R11 body, strided groups) ----
        int sub = lane & 15;        // 16-B chunk within the 256-B field
        int rr = lane >> 4;         // row within group of 4
        int gw = idx * 4 + wid;
        const int NW = SBLK * 4;

        // prefetch all 6 row-mask predicates (mask is 786 KB, L2-resident)
        float mk[6];
        #pragma unroll
        for (int j = 0; j < 6; ++j) mk[j] = mask[4 * (gw + j * NW) + rr];

        float a0 = 0.0f, a12 = 0.0f;
        #pragma unroll
        for (int h = 0; h < 3; ++h) {
            size_t b0 = (size_t)(4 * (gw + (2 * h) * NW) + rr) * AA;
            size_t b1 = (size_t)(4 * (gw + (2 * h + 1) * NW) + rr) * AA;
            bool m0 = mk[2 * h] > 0.0f, m1 = mk[2 * h + 1] > 0.0f;

            float4a pv0 = ld4(pred + b0 + 2 * KK + sub * 4);
            float4a gv0 = ld4(gt   + b0 + 2 * KK + sub * 4);
            float4a pv1 = ld4(pred + b1 + 2 * KK + sub * 4);
            float4a gv1 = ld4(gt   + b1 + 2 * KK + sub * 4);
            float pc0 = pred[b0 + 3 * KK];
            float pc1 = pred[b1 + 3 * KK];
            float4a pX0 = {0,0,0,0}, gX0 = {0,0,0,0}, pX1 = {0,0,0,0}, gX1 = {0,0,0,0};
            if (m0) { pX0 = ld4(pred + b0 + sub * 4); gX0 = ld4(gt + b0 + sub * 4); }
            if (m1) { pX1 = ld4(pred + b1 + sub * 4); gX1 = ld4(gt + b1 + sub * 4); }

            // BCE select values; all in (0.01, 1.0) -> product of 8 safe
            float s0 = gv0.x > 0.0f ? pv0.x + EPSF : 1.0f - pv0.x + EPSF;
            float s1 = gv0.y > 0.0f ? pv0.y + EPSF : 1.0f - pv0.y + EPSF;
            float s2 = gv0.z > 0.0f ? pv0.z + EPSF : 1.0f - pv0.z + EPSF;
            float s3 = gv0.w > 0.0f ? pv0.w + EPSF : 1.0f - pv0.w + EPSF;
            float s4 = gv1.x > 0.0f ? pv1.x + EPSF : 1.0f - pv1.x + EPSF;
            float s5 = gv1.y > 0.0f ? pv1.y + EPSF : 1.0f - pv1.y + EPSF;
            float s6 = gv1.z > 0.0f ? pv1.z + EPSF : 1.0f - pv1.z + EPSF;
            float s7 = gv1.w > 0.0f ? pv1.w + EPSF : 1.0f - pv1.w + EPSF;
            a0 += __logf(((s0 * s1) * (s2 * s3)) * ((s4 * s5) * (s6 * s7)));

            if (sub == 0) {
                float c0 = m0 ? pc0 + EPSF : 1.0f - pc0 + EPSF;
                float c1 = m1 ? pc1 + EPSF : 1.0f - pc1 + EPSF;
                a12 -= __logf(c0 * c1);
            }

            if (m0)
                a12 += gv0.x * fabsf(pX0.x - gX0.x) + gv0.y * fabsf(pX0.y - gX0.y)
                     + gv0.z * fabsf(pX0.z - gX0.z) + gv0.w * fabsf(pX0.w - gX0.w);
            if (m1)
                a12 += gv1.x * fabsf(pX1.x - gX1.x) + gv1.y * fabsf(pX1.y - gX1.y)
                     + gv1.z * fabsf(pX1.z - gX1.z) + gv1.w * fabsf(pX1.w - gX1.w);
        }
        local = a12 - a0 * (1.0f / KK);
    }

    // ---- wave reduce (no barriers) + cross-wave + one atomic per block ----
    #pragma unroll
    for (int d = 32; d > 0; d >>= 1) local += __shfl_xor(local, d);

    __shared__ float s_w[4];
    if (lane == 0) s_w[wid] = local;
    __syncthreads();
    if (tid == 0) {
        float tot = s_w[0] + s_w[1] + s_w[2] + s_w[3];
        atomicAdd(&part[blockIdx.x & (NPART - 1)], (double)tot);
    }
}

__global__ __launch_bounds__(256) void k_final(const double* __restrict__ part,
                                               float* __restrict__ out) {
    int tid = threadIdx.x;
    __shared__ double red[256];
    red[tid] = part[tid];
    __syncthreads();
    for (int s = 128; s > 0; s >>= 1) {
        if (tid < s) red[tid] += red[tid + s];
        __syncthreads();
    }
    if (tid == 0) out[0] = (float)red[0];
}

extern "C" void kernel_launch(void* const* d_in, const int* in_sizes, int n_in,
                              void* d_out, int out_size, void* d_ws, size_t ws_size,
                              hipStream_t stream) {
    const float* pred = (const float*)d_in[0];
    const float* gt   = (const float*)d_in[1];
    const float* hcam = (const float*)d_in[2];
    const float* ax   = (const float*)d_in[3];
    const float* ay   = (const float*)d_in[4];
    const float* xstd = (const float*)d_in[5];
    const float* zstd = (const float*)d_in[6];
    float* out = (float*)d_out;

    char* ws = (char*)d_ws;
    double* part = (double*)ws;
    int* nsel   = (int*)(ws + 2048);
    int* ncols  = (int*)(ws + 3072);
    int* S      = (int*)(ws + 4096);
    int* Ck     = (int*)(ws + 266240);
    float* mask = (float*)(ws + 331776);

    hipLaunchKernelGGL(k_meta, dim3(NN), dim3(1024), 0, stream,
                       gt, nsel, ncols, S, Ck, part, mask);
    hipLaunchKernelGGL(k_fused, dim3(NBLK), dim3(256), 0, stream,
                       pred, gt, mask, hcam, ax, ay, xstd, zstd,
                       nsel, ncols, S, Ck, part);
    hipLaunchKernelGGL(k_final, dim3(1), dim3(256), 0, stream, part, out);
}

// Round 14
// 48.894 us; speedup vs baseline: 1.2984x; 1.0096x over previous
//
#include <hip/hip_runtime.h>
#include <math.h>

#define NN 256
#define XX 256
#define TT 3
#define KK 64
#define AA 193          // 3*K+1
#define EPSF 1e-9f
#define NPART 256
#define SBLK 2048       // stream-role blocks
#define PBLK 2048       // pairs-role blocks (8 per n)
#define NBLK (SBLK + PBLK)   // 4096 = 8 * 512 (bijective XCD swizzle)
#define NWAVE 8192      // waves per role
#define SGRP 5          // stream groups per stream wave
#define PGRP_BASE (NWAVE * SGRP)   // 40960; pairs waves cover [40960, 49152)

// ws layout (bytes):
// [0, 2048)            double part[256]
// [2048, 3072)         int nsel[256]
// [3072, 4096)         int ncols[256]
// [4096, 266240)       int S[256][256]      (full `order` per n)
// [266240, 331776)     int Ck[256][64]      (full `corder` per n)
// [331776, 1118208)    float mask[196608]   (gt_class value per row, 0.0/1.0)

typedef float float4a __attribute__((ext_vector_type(4)));

__device__ __forceinline__ float4a ld4(const float* p) {
    float4a v;
    __builtin_memcpy(&v, p, 16);   // align-4 safe
    return v;
}

// one stream group (4 rows), single-depth
__device__ __forceinline__ void stream1(const float* __restrict__ pred,
                                        const float* __restrict__ gt,
                                        size_t b, bool m, int sub,
                                        float& a0, float& a12) {
    float4a pv = ld4(pred + b + 2 * KK + sub * 4);
    float4a gv = ld4(gt   + b + 2 * KK + sub * 4);
    float pc = pred[b + 3 * KK];
    float4a pX = {0,0,0,0}, gX = {0,0,0,0};
    if (m) { pX = ld4(pred + b + sub * 4); gX = ld4(gt + b + sub * 4); }

    float s0 = gv.x > 0.0f ? pv.x + EPSF : 1.0f - pv.x + EPSF;
    float s1 = gv.y > 0.0f ? pv.y + EPSF : 1.0f - pv.y + EPSF;
    float s2 = gv.z > 0.0f ? pv.z + EPSF : 1.0f - pv.z + EPSF;
    float s3 = gv.w > 0.0f ? pv.w + EPSF : 1.0f - pv.w + EPSF;
    a0 += __logf((s0 * s1) * (s2 * s3));
    if (sub == 0)
        a12 -= __logf(m ? pc + EPSF : 1.0f - pc + EPSF);
    if (m)
        a12 += gv.x * fabsf(pX.x - gX.x) + gv.y * fabsf(pX.y - gX.y)
             + gv.z * fabsf(pX.z - gX.z) + gv.w * fabsf(pX.w - gX.w);
}

// two stream groups, loads batched back-to-back (2-deep MLP)
__device__ __forceinline__ void stream2(const float* __restrict__ pred,
                                        const float* __restrict__ gt,
                                        size_t b0, size_t b1, bool m0, bool m1,
                                        int sub, float& a0, float& a12) {
    float4a pv0 = ld4(pred + b0 + 2 * KK + sub * 4);
    float4a gv0 = ld4(gt   + b0 + 2 * KK + sub * 4);
    float4a pv1 = ld4(pred + b1 + 2 * KK + sub * 4);
    float4a gv1 = ld4(gt   + b1 + 2 * KK + sub * 4);
    float pc0 = pred[b0 + 3 * KK];
    float pc1 = pred[b1 + 3 * KK];
    float4a pX0 = {0,0,0,0}, gX0 = {0,0,0,0}, pX1 = {0,0,0,0}, gX1 = {0,0,0,0};
    if (m0) { pX0 = ld4(pred + b0 + sub * 4); gX0 = ld4(gt + b0 + sub * 4); }
    if (m1) { pX1 = ld4(pred + b1 + sub * 4); gX1 = ld4(gt + b1 + sub * 4); }

    float s0 = gv0.x > 0.0f ? pv0.x + EPSF : 1.0f - pv0.x + EPSF;
    float s1 = gv0.y > 0.0f ? pv0.y + EPSF : 1.0f - pv0.y + EPSF;
    float s2 = gv0.z > 0.0f ? pv0.z + EPSF : 1.0f - pv0.z + EPSF;
    float s3 = gv0.w > 0.0f ? pv0.w + EPSF : 1.0f - pv0.w + EPSF;
    float s4 = gv1.x > 0.0f ? pv1.x + EPSF : 1.0f - pv1.x + EPSF;
    float s5 = gv1.y > 0.0f ? pv1.y + EPSF : 1.0f - pv1.y + EPSF;
    float s6 = gv1.z > 0.0f ? pv1.z + EPSF : 1.0f - pv1.z + EPSF;
    float s7 = gv1.w > 0.0f ? pv1.w + EPSF : 1.0f - pv1.w + EPSF;
    a0 += __logf(((s0 * s1) * (s2 * s3)) * ((s4 * s5) * (s6 * s7)));

    if (sub == 0) {
        float c0 = m0 ? pc0 + EPSF : 1.0f - pc0 + EPSF;
        float c1 = m1 ? pc1 + EPSF : 1.0f - pc1 + EPSF;
        a12 -= __logf(c0 * c1);
    }
    if (m0)
        a12 += gv0.x * fabsf(pX0.x - gX0.x) + gv0.y * fabsf(pX0.y - gX0.y)
             + gv0.z * fabsf(pX0.z - gX0.z) + gv0.w * fabsf(pX0.w - gX0.w);
    if (m1)
        a12 += gv1.x * fabsf(pX1.x - gX1.x) + gv1.y * fabsf(pX1.y - gX1.y)
             + gv1.z * fabsf(pX1.z - gX1.z) + gv1.w * fabsf(pX1.w - gX1.w);
}

// 1024 threads: phase 1 on waves 0-3 (one x per thread), phase 2 on all 16 waves.
__global__ __launch_bounds__(1024) void k_meta(const float* __restrict__ gt,
                                               int* __restrict__ nselArr,
                                               int* __restrict__ ncolsArr,
                                               int* __restrict__ S,
                                               int* __restrict__ Ck,
                                               double* __restrict__ part,
                                               float* __restrict__ mask) {
    int n = blockIdx.x;
    int tid = threadIdx.x;
    int lane = tid & 63;
    int wave = tid >> 6;
    bool isP1 = wave < 4;          // tid < 256, wave-uniform

    // zero the partial-sum buffer (consumers launch after us on the stream)
    if (n == 0 && tid < NPART) part[tid] = 0.0;

    __shared__ int s_S[XX];
    __shared__ int s_cnt[4];
    __shared__ float s_red[16 * 64];
    __shared__ int s_nsel;

    // ---- phase 1a: load gc, write mask, ballot ----
    bool selx = false;
    unsigned long long bal = 0;
    if (isP1) {
        int x = tid;
        size_t rb = ((size_t)(n * XX + x) * TT) * AA;
        float gc0 = gt[rb + 3 * KK];
        float gc1 = gt[rb + AA + 3 * KK];
        float gc2 = gt[rb + 2 * AA + 3 * KK];
        int rowid = (n * XX + x) * TT;
        mask[rowid + 0] = gc0;
        mask[rowid + 1] = gc1;
        mask[rowid + 2] = gc2;
        selx = gc0 > 0.0f;
        bal = __ballot(selx);
        if (lane == 0) s_cnt[wave] = __popcll(bal);
    }
    __syncthreads();

    // ---- phase 1b: stable partition (the `order` array) ----
    if (isP1) {
        int c0 = s_cnt[0], c1 = s_cnt[1], c2 = s_cnt[2], c3 = s_cnt[3];
        int nsel_n = c0 + c1 + c2 + c3;
        int selbase = (wave > 0 ? c0 : 0) + (wave > 1 ? c1 : 0) + (wave > 2 ? c2 : 0);
        unsigned long long ltmask = (1ull << lane) - 1ull;
        int pos;
        if (selx) pos = selbase + __popcll(bal & ltmask);
        else      pos = nsel_n + (64 * wave - selbase) + __popcll((~bal) & ltmask);
        s_S[pos] = tid;
        if (tid == 0) { s_nsel = nsel_n; nselArr[n] = nsel_n; }
    }
    __syncthreads();
    if (tid < XX) S[n * XX + tid] = s_S[tid];

    // ---- phase 2: column sums over selected rows (16 waves) ----
    int nsl = s_nsel;
    float partial = 0.0f;
    for (int i = wave; i < nsl; i += 16) {
        int xs = s_S[i];
        size_t base = ((size_t)(n * XX + xs) * TT) * AA + 2 * KK + lane;
        partial += gt[base] + gt[base + AA] + gt[base + 2 * AA];
    }
    s_red[tid] = partial;
    __syncthreads();

    // ---- phase 3: keep + stable column partition (the `corder` array) ----
    if (tid < KK) {
        float tot = 0.0f;
        #pragma unroll
        for (int w = 0; w < 16; ++w) tot += s_red[tid + 64 * w];
        int nrows = nsl * TT;
        bool keep = (tot >= (float)nrows) || (tid < 5);
        unsigned long long kb = __ballot(keep);
        int nc = __popcll(kb);
        unsigned long long lt = (1ull << tid) - 1ull;
        int cpos = keep ? __popcll(kb & lt) : nc + __popcll((~kb) & lt);
        Ck[n * KK + cpos] = tid;
        if (tid == 0) ncolsArr[n] = nc;
    }
}

// R13 + role load-balancing: pairs waves, after finishing their gathers, each
// process 1 stream group (groups [40960, 49152)); stream waves do 5 groups.
// Eliminates the pairs-idle tail. XCD chunk swizzle retained (proven +3.5us).
__global__ __launch_bounds__(256) void k_fused(const float* __restrict__ pred,
                                               const float* __restrict__ gt,
                                               const float* __restrict__ mask,
                                               const float* __restrict__ hcam_arr,
                                               const float* __restrict__ ax,
                                               const float* __restrict__ ay,
                                               const float* __restrict__ xstd,
                                               const float* __restrict__ zstd,
                                               const int* __restrict__ nselArr,
                                               const int* __restrict__ ncolsArr,
                                               const int* __restrict__ S,
                                               const int* __restrict__ Ck,
                                               double* __restrict__ part) {
    int tid = threadIdx.x;
    int lane = tid & 63;
    int wid = tid >> 6;
    // bijective XCD chunk swizzle (NBLK = 4096 = 8 * 512)
    int w = ((blockIdx.x & 7) << 9) | (blockIdx.x >> 3);
    int role_pairs = w & 1;
    int idx = w >> 1;                   // 0..2047 within each role
    int sub = lane & 15;
    int rr = lane >> 4;

    float local = 0.0f;

    if (role_pairs) {
        // ---- pairs role: 8 blocks per n, 32 waves per n ----
        float accp = 0.0f;
        int n = idx >> 3;
        int waveIdx = ((idx & 7) << 2) | wid;          // 0..31
        int nrows = nselArr[n] * TT;
        int ncols = ncolsArr[n];
        int k = Ck[n * KK + lane];
        float inv_h = 1.0f / hcam_arr[n];
        float zs = zstd[k], xs = xstd[k], ayk = ay[k];
        float xstd0 = xstd[0];

        for (int i = 0; i < 24; ++i) {
            int p = i * 32 + waveIdx;                  // covers 0..767
            if (p + 1 >= nrows) break;                 // wave-uniform, monotone
            int r1 = p + 1;
            int x0 = S[n * XX + p / 3];  int t0 = p % 3;
            int x1 = S[n * XX + r1 / 3]; int t1 = r1 % 3;
            size_t b0 = ((size_t)(n * XX + x0) * TT + t0) * AA;
            size_t b1 = ((size_t)(n * XX + x1) * TT + t1) * AA;
            float pz0 = pred[b0 + KK + k], gx0 = gt[b0 + k];
            float pz1 = pred[b1 + KK + k], gx1 = gt[b1 + k];
            float ax0 = ax[x0], ax1 = ax[x1];
            float Z0 = pz0 * zs, Z1 = pz1 * zs;
            float sc0 = 1.0f - Z0 * inv_h, sc1 = 1.0f - Z1 * inv_h;
            float L0 = sc0 * (gx0 * xs + ax0);
            float L1 = sc1 * (gx1 * xs + ax1);
            float Y0 = sc0 * ayk;
            float l00 = gt[b0] * xstd0 + ax0;
            float l01 = gt[b1] * xstd0 + ax1;
            float width0 = fabsf(l01 - l00);

            float lm1 = __shfl_up(L0, 1);
            float ym1 = __shfl_up(Y0, 1);
            float y1v = __shfl(Y0, 1);
            float dYc, lc;
            if (lane == 0) {
                dYc = fabsf(y1v - Y0);
                lc = dYc;
            } else {
                dYc = fabsf(Y0 - ym1);
                float dx = L0 - lm1;
                lc = sqrtf(dx * dx + dYc * dYc);
            }
            float wv = fabsf(L1 - L0) * dYc / (lc + EPSF);
            float wm1 = __shfl_up(wv, 1);
            float werr = fabsf(wv - (lane == 0 ? width0 : wm1));
            float dZ = fabsf(Z1 - Z0);
            if (lane < ncols) accp += werr + dZ;
        }

        // ---- tail stream group: one group per pairs wave ----
        int g = PGRP_BASE + idx * 4 + wid;
        float mkp = mask[4 * g + rr];
        float a0 = 0.0f, a12 = 0.0f;
        stream1(pred, gt, (size_t)(4 * g + rr) * AA, mkp > 0.0f, sub, a0, a12);
        local = 5.0f * accp + a12 - a0 * (1.0f / KK);
    } else {
        // ---- stream role: 5 strided groups per wave ----
        int gw = idx * 4 + wid;            // 0..8191

        float mk[SGRP];
        #pragma unroll
        for (int j = 0; j < SGRP; ++j) mk[j] = mask[4 * (gw + j * NWAVE) + rr];

        float a0 = 0.0f, a12 = 0.0f;
        #pragma unroll
        for (int h = 0; h < 2; ++h) {
            size_t b0 = (size_t)(4 * (gw + (2 * h) * NWAVE) + rr) * AA;
            size_t b1 = (size_t)(4 * (gw + (2 * h + 1) * NWAVE) + rr) * AA;
            stream2(pred, gt, b0, b1,
                    mk[2 * h] > 0.0f, mk[2 * h + 1] > 0.0f, sub, a0, a12);
        }
        stream1(pred, gt, (size_t)(4 * (gw + 4 * NWAVE) + rr) * AA,
                mk[4] > 0.0f, sub, a0, a12);
        local = a12 - a0 * (1.0f / KK);
    }

    // ---- wave reduce (no barriers) + cross-wave + one atomic per block ----
    #pragma unroll
    for (int d = 32; d > 0; d >>= 1) local += __shfl_xor(local, d);

    __shared__ float s_w[4];
    if (lane == 0) s_w[wid] = local;
    __syncthreads();
    if (tid == 0) {
        float tot = s_w[0] + s_w[1] + s_w[2] + s_w[3];
        atomicAdd(&part[blockIdx.x & (NPART - 1)], (double)tot);
    }
}

__global__ __launch_bounds__(256) void k_final(const double* __restrict__ part,
                                               float* __restrict__ out) {
    int tid = threadIdx.x;
    __shared__ double red[256];
    red[tid] = part[tid];
    __syncthreads();
    for (int s = 128; s > 0; s >>= 1) {
        if (tid < s) red[tid] += red[tid + s];
        __syncthreads();
    }
    if (tid == 0) out[0] = (float)red[0];
}

extern "C" void kernel_launch(void* const* d_in, const int* in_sizes, int n_in,
                              void* d_out, int out_size, void* d_ws, size_t ws_size,
                              hipStream_t stream) {
    const float* pred = (const float*)d_in[0];
    const float* gt   = (const float*)d_in[1];
    const float* hcam = (const float*)d_in[2];
    const float* ax   = (const float*)d_in[3];
    const float* ay   = (const float*)d_in[4];
    const float* xstd = (const float*)d_in[5];
    const float* zstd = (const float*)d_in[6];
    float* out = (float*)d_out;

    char* ws = (char*)d_ws;
    double* part = (double*)ws;
    int* nsel   = (int*)(ws + 2048);
    int* ncols  = (int*)(ws + 3072);
    int* S      = (int*)(ws + 4096);
    int* Ck     = (int*)(ws + 266240);
    float* mask = (float*)(ws + 331776);

    hipLaunchKernelGGL(k_meta, dim3(NN), dim3(1024), 0, stream,
                       gt, nsel, ncols, S, Ck, part, mask);
    hipLaunchKernelGGL(k_fused, dim3(NBLK), dim3(256), 0, stream,
                       pred, gt, mask, hcam, ax, ay, xstd, zstd,
                       nsel, ncols, S, Ck, part);
    hipLaunchKernelGGL(k_final, dim3(1), dim3(256), 0, stream, part, out);
}